// Round 9
// baseline (80742.975 us; speedup 1.0000x reference)
//
#include <hip/hip_runtime.h>
#include <math.h>

#define B_   64
#define S_   512
#define IN_  512
#define H_   1024
#define WLK_ (H_ + 128)
#define NBLK 256
#define NTHR 512

typedef unsigned long long ull;
typedef float f32x4 __attribute__((ext_vector_type(4)));

// ---- static device scratch ----
__device__ float g_xT[(size_t)S_ * IN_ * B_];   // [s][k][b]
__device__ float g_h0T[H_ * B_];                // [k][b]
__device__ float g_hT[2][H_ * B_];              // [k][b]
__device__ float g_hhatT[H_ * B_];              // [j][b]
__device__ float g_zprojT[H_ * B_];             // [j][b] includes b_lin
__device__ unsigned g_bar[2 * S_][256];         // 8 live counters/slot, 128B apart

// device-coherent 8B ops: relaxed agent-scope atomics. R7-proven: L2-served
// (FETCH 1.3GB) and correct. R8's asm sc1 loads bypassed L2 (FETCH 71GB) -> dead.
__device__ __forceinline__ ull coh_ld(const ull* p) {
    return __hip_atomic_load(p, __ATOMIC_RELAXED, __HIP_MEMORY_SCOPE_AGENT);
}
__device__ __forceinline__ f32x4 mk4(ull lo, ull hi) {
    union { ull u[2]; f32x4 f; } v; v.u[0] = lo; v.u[1] = hi; return v.f;
}
__device__ __forceinline__ void coh_store2(float* p, float x, float y) {
    union { float2 f; ull u; } v; v.f = make_float2(x, y);
    __hip_atomic_store((ull*)p, v.u, __ATOMIC_RELAXED, __HIP_MEMORY_SCOPE_AGENT);
}

#define SB() __builtin_amdgcn_sched_barrier(0)

#define F4(AC, WS) AC.x=fmaf(WS,a.x,AC.x); AC.y=fmaf(WS,a.y,AC.y); AC.z=fmaf(WS,a.z,AC.z); AC.w=fmaf(WS,a.w,AC.w);

// issue 16 coherent 8B loads covering k-iterations [8c, 8c+8)
// per-iter stride: 32 k-rows * 64 floats = 2048 floats = 1024 ull
#define ISS(P, c, v0,v1,v2,v3,v4,v5,v6,v7,v8,v9,v10,v11,v12,v13,v14,v15) do { \
    const ull* p_ = (P) + (size_t)(c) * 8192;       \
    v0 = coh_ld(p_);        v1 = coh_ld(p_ + 1);    \
    v2 = coh_ld(p_ + 1024); v3 = coh_ld(p_ + 1025); \
    v4 = coh_ld(p_ + 2048); v5 = coh_ld(p_ + 2049); \
    v6 = coh_ld(p_ + 3072); v7 = coh_ld(p_ + 3073); \
    v8 = coh_ld(p_ + 4096); v9 = coh_ld(p_ + 4097); \
    v10= coh_ld(p_ + 5120); v11= coh_ld(p_ + 5121); \
    v12= coh_ld(p_ + 6144); v13= coh_ld(p_ + 6145); \
    v14= coh_ld(p_ + 7168); v15= coh_ld(p_ + 7169); \
    SB(); } while (0)

#define RED1(AC, cc, NC) { f32x4 v = AC; \
    v.x += __shfl_xor(v.x,16); v.y += __shfl_xor(v.y,16); \
    v.z += __shfl_xor(v.z,16); v.w += __shfl_xor(v.w,16); \
    v.x += __shfl_xor(v.x,32); v.y += __shfl_xor(v.y,32); \
    v.z += __shfl_xor(v.z,32); v.w += __shfl_xor(v.w,32); \
    if (ln < 16) *(f32x4*)&red[(wv * NC + cc) * 64 + (ln << 2)] = v; }

// ---------------- prologue 1: transpose inputs [B][S][IN] -> xT [S][IN][B] ----
__global__ void pre_transpose_x(const float* __restrict__ in) {
    __shared__ float lds[64][65];
    int s  = blockIdx.x >> 3;
    int k0 = (blockIdx.x & 7) << 6;
    int tid = threadIdx.x;
    int kk = tid & 63, bq = tid >> 6;
    for (int b = bq; b < 64; b += 4)
        lds[kk][b] = in[((size_t)b * S_ + s) * IN_ + k0 + kk];
    __syncthreads();
    int bb = tid & 63, kq = tid >> 6;
    for (int k = kq; k < 64; k += 4)
        g_xT[((size_t)s * IN_ + k0 + k) * B_ + bb] = lds[k][bb];
}

// ---------------- prologue 2: z_projT (incl b_lin), h0T, zero barriers ------
__global__ void pre_misc(const float* __restrict__ z, const float* __restrict__ Wlin,
                         const float* __restrict__ blin, const float* __restrict__ h0) {
    __shared__ float zT[128][65];
    int j = blockIdx.x;      // 0..1023
    int b = threadIdx.x;     // 0..63
    for (int i = 0; i < 128; ++i) {
        int idx = b + (i << 6);
        zT[idx & 127][idx >> 7] = z[idx];
    }
    __syncthreads();
    float acc = blin[j];
    const float* w = Wlin + (size_t)j * WLK_ + H_;
    for (int k = 0; k < 128; ++k)
        acc = fmaf(zT[k][b], w[k], acc);
    g_zprojT[j * 64 + b] = acc;
    g_h0T[j * 64 + b]    = h0[(size_t)b * H_ + j];
    for (int i = b; i < 256; i += 64)
        g_bar[j][i] = 0;
}

// 12-col GEMM over K=512, NORMAL cached loads (x is read-only) — unchanged R7
__device__ __forceinline__ void gemm12n(const float* __restrict__ src,
                                        const float* wl,
                                        const float* bias_l, float* dst,
                                        float* red, int tid) {
    const int bq = tid & 15, kq = tid >> 4;
    const int wv = tid >> 6, ln = tid & 63;
    const float* ap = src + (kq << 6) + (bq << 2);
    const float* wp = wl + kq * 12;
    f32x4 acc[12];
    #pragma unroll
    for (int c = 0; c < 12; ++c) acc[c] = (f32x4){0.f,0.f,0.f,0.f};
    #pragma unroll 4
    for (int i = 0; i < 16; ++i) {
        f32x4 a  = *(const f32x4*)ap;  ap += 32 * 64;
        f32x4 w0 = *(const f32x4*)(wp + 0);
        f32x4 w1 = *(const f32x4*)(wp + 4);
        f32x4 w2 = *(const f32x4*)(wp + 8);  wp += 32 * 12;
        F4(acc[0],w0.x) F4(acc[1],w0.y) F4(acc[2],w0.z)  F4(acc[3],w0.w)
        F4(acc[4],w1.x) F4(acc[5],w1.y) F4(acc[6],w1.z)  F4(acc[7],w1.w)
        F4(acc[8],w2.x) F4(acc[9],w2.y) F4(acc[10],w2.z) F4(acc[11],w2.w)
    }
    #pragma unroll
    for (int c = 0; c < 12; ++c) {
        f32x4 v = acc[c];
        v.x += __shfl_xor(v.x,16); v.y += __shfl_xor(v.y,16);
        v.z += __shfl_xor(v.z,16); v.w += __shfl_xor(v.w,16);
        v.x += __shfl_xor(v.x,32); v.y += __shfl_xor(v.y,32);
        v.z += __shfl_xor(v.z,32); v.w += __shfl_xor(v.w,32);
        if (ln < 16) *(f32x4*)&red[(wv * 12 + c) * 64 + (ln << 2)] = v;
    }
    __syncthreads();
    for (int o = tid; o < 768; o += NTHR) {
        int c = o >> 6, b = o & 63;
        float s = bias_l[c];
        #pragma unroll
        for (int w = 0; w < 8; ++w) s += red[(w * 12 + c) * 64 + b];
        dst[o] = s;
    }
}

// 12-col GEMM over K=1024, coherent loads, 2-deep 16-load chunk pipeline
__device__ __forceinline__ void gemm12c(const float* src, const float* wl,
                                        const float* bias_l, float* dst,
                                        float* red, int tid) {
    const int bq = tid & 15, kq = tid >> 4;
    const int wv = tid >> 6, ln = tid & 63;
    const ull* base = (const ull*)(src + (kq << 6) + (bq << 2));
    const float* wp = wl + kq * 12;
    f32x4 c0={0,0,0,0},c1={0,0,0,0},c2={0,0,0,0},c3={0,0,0,0},c4={0,0,0,0},c5={0,0,0,0},
          c6={0,0,0,0},c7={0,0,0,0},c8={0,0,0,0},c9={0,0,0,0},c10={0,0,0,0},c11={0,0,0,0};
    ull a0,a1,a2,a3,a4,a5,a6,a7,a8,a9,a10,a11,a12,a13,a14,a15;
    ull b0,b1,b2,b3,b4,b5,b6,b7,b8,b9,b10,b11,b12,b13,b14,b15;
#define FMA12v(AV) do { f32x4 a = (AV); \
    f32x4 w0 = *(const f32x4*)(wp); \
    f32x4 w1 = *(const f32x4*)(wp + 4); \
    f32x4 w2 = *(const f32x4*)(wp + 8); \
    wp += 32 * 12; \
    F4(c0,w0.x) F4(c1,w0.y) F4(c2,w0.z)  F4(c3,w0.w) \
    F4(c4,w1.x) F4(c5,w1.y) F4(c6,w1.z)  F4(c7,w1.w) \
    F4(c8,w2.x) F4(c9,w2.y) F4(c10,w2.z) F4(c11,w2.w) } while (0)
#define FMA_A8 FMA12v(mk4(a0,a1)); FMA12v(mk4(a2,a3)); FMA12v(mk4(a4,a5)); FMA12v(mk4(a6,a7)); \
               FMA12v(mk4(a8,a9)); FMA12v(mk4(a10,a11)); FMA12v(mk4(a12,a13)); FMA12v(mk4(a14,a15));
#define FMA_B8 FMA12v(mk4(b0,b1)); FMA12v(mk4(b2,b3)); FMA12v(mk4(b4,b5)); FMA12v(mk4(b6,b7)); \
               FMA12v(mk4(b8,b9)); FMA12v(mk4(b10,b11)); FMA12v(mk4(b12,b13)); FMA12v(mk4(b14,b15));
    ISS(base, 0, a0,a1,a2,a3,a4,a5,a6,a7,a8,a9,a10,a11,a12,a13,a14,a15);
    ISS(base, 1, b0,b1,b2,b3,b4,b5,b6,b7,b8,b9,b10,b11,b12,b13,b14,b15);
    FMA_A8
    ISS(base, 2, a0,a1,a2,a3,a4,a5,a6,a7,a8,a9,a10,a11,a12,a13,a14,a15);
    FMA_B8
    ISS(base, 3, b0,b1,b2,b3,b4,b5,b6,b7,b8,b9,b10,b11,b12,b13,b14,b15);
    FMA_A8
    FMA_B8
#undef FMA_A8
#undef FMA_B8
#undef FMA12v
    RED1(c0,0,12)  RED1(c1,1,12)  RED1(c2,2,12)   RED1(c3,3,12)
    RED1(c4,4,12)  RED1(c5,5,12)  RED1(c6,6,12)   RED1(c7,7,12)
    RED1(c8,8,12)  RED1(c9,9,12)  RED1(c10,10,12) RED1(c11,11,12)
    __syncthreads();
    for (int o = tid; o < 768; o += NTHR) {
        int c = o >> 6, b = o & 63;
        float s = bias_l[c];
        #pragma unroll
        for (int w = 0; w < 8; ++w) s += red[(w * 12 + c) * 64 + b];
        dst[o] = s;
    }
}

// ---------------- persistent recurrence kernel ------------------------------
__launch_bounds__(NTHR, 1)
__global__ void skipgru_2ph(const float* __restrict__ Wlin, const float* __restrict__ Wih,
                            const float* __restrict__ bih,  const float* __restrict__ Whh,
                            const float* __restrict__ bhh,  float* __restrict__ out) {
    __shared__ float wA[H_ * 4];        // 16 KB [k][c<4]
    __shared__ float wB[H_ * 12];       // 48 KB [k][c<12]
    __shared__ float wX[IN_ * 12];      // 24 KB [k][c<12]
    __shared__ float red[8 * 12 * 64];  // 24 KB
    __shared__ float gh_l[12 * 64];
    __shared__ float gi_a[12 * 64];
    __shared__ float gi_b[12 * 64];
    __shared__ float hh_l[4 * 64];
    __shared__ float hn_l[4 * 64];
    __shared__ float zp_l[4 * 64];
    __shared__ float bhh_l[12];
    __shared__ float bih_l[12];

    const int tid = threadIdx.x;
    const int jb  = blockIdx.x << 2;
    const int bq  = tid & 15;
    const int kq  = tid >> 4;
    const int wv  = tid >> 6, ln = tid & 63;
    const int barlane = (blockIdx.x & 7) << 5;

    for (int c = 0; c < 4; ++c) {
        const float* src = Wlin + (size_t)(jb + c) * WLK_;
        for (int k = tid; k < H_; k += NTHR) wA[k * 4 + c] = src[k];
    }
    for (int c = 0; c < 12; ++c) {
        const float* src = Whh + (size_t)((c >> 2) * H_ + jb + (c & 3)) * H_;
        for (int k = tid; k < H_; k += NTHR) wB[k * 12 + c] = src[k];
    }
    for (int c = 0; c < 12; ++c) {
        const float* src = Wih + (size_t)((c >> 2) * H_ + jb + (c & 3)) * IN_;
        for (int k = tid; k < IN_; k += NTHR) wX[k * 12 + c] = src[k];
    }
    if (tid < 256) zp_l[tid] = g_zprojT[(jb + (tid >> 6)) * 64 + (tid & 63)];
    if (tid < 12) {
        bhh_l[tid] = bhh[(tid >> 2) * H_ + jb + (tid & 3)];
        bih_l[tid] = bih[(tid >> 2) * H_ + jb + (tid & 3)];
    }
    __syncthreads();

    gemm12n(g_xT, wX, bih_l, gi_a, red, tid);
    __syncthreads();

    for (int t = 0; t < S_; ++t) {
        const float* hs = (t == 0) ? g_h0T : g_hT[t & 1];
        const float* gi_cur = (t & 1) ? gi_b : gi_a;
        float*       gi_nxt = (t & 1) ? gi_a : gi_b;

        // ---- P1: h_hat, 4 cols, K=1024, coherent pipelined loads ----
        {
            const ull* base = (const ull*)(hs + (kq << 6) + (bq << 2));
            const float* wp = wA + kq * 4;
            f32x4 c0={0,0,0,0},c1={0,0,0,0},c2={0,0,0,0},c3={0,0,0,0};
            ull a0,a1,a2,a3,a4,a5,a6,a7,a8,a9,a10,a11,a12,a13,a14,a15;
            ull b0,b1,b2,b3,b4,b5,b6,b7,b8,b9,b10,b11,b12,b13,b14,b15;
#define FMA4v(AV) do { f32x4 a = (AV); \
    f32x4 w = *(const f32x4*)wp;  wp += 32 * 4; \
    F4(c0,w.x) F4(c1,w.y) F4(c2,w.z) F4(c3,w.w) } while (0)
#define P1_A8 FMA4v(mk4(a0,a1)); FMA4v(mk4(a2,a3)); FMA4v(mk4(a4,a5)); FMA4v(mk4(a6,a7)); \
              FMA4v(mk4(a8,a9)); FMA4v(mk4(a10,a11)); FMA4v(mk4(a12,a13)); FMA4v(mk4(a14,a15));
#define P1_B8 FMA4v(mk4(b0,b1)); FMA4v(mk4(b2,b3)); FMA4v(mk4(b4,b5)); FMA4v(mk4(b6,b7)); \
              FMA4v(mk4(b8,b9)); FMA4v(mk4(b10,b11)); FMA4v(mk4(b12,b13)); FMA4v(mk4(b14,b15));
            ISS(base, 0, a0,a1,a2,a3,a4,a5,a6,a7,a8,a9,a10,a11,a12,a13,a14,a15);
            ISS(base, 1, b0,b1,b2,b3,b4,b5,b6,b7,b8,b9,b10,b11,b12,b13,b14,b15);
            P1_A8
            ISS(base, 2, a0,a1,a2,a3,a4,a5,a6,a7,a8,a9,a10,a11,a12,a13,a14,a15);
            P1_B8
            ISS(base, 3, b0,b1,b2,b3,b4,b5,b6,b7,b8,b9,b10,b11,b12,b13,b14,b15);
            P1_A8
            P1_B8
#undef P1_A8
#undef P1_B8
#undef FMA4v
            RED1(c0,0,4) RED1(c1,1,4) RED1(c2,2,4) RED1(c3,3,4)
        }
        __syncthreads();
        if (tid < 256) {
            int c = tid >> 6, b = tid & 63;
            float s = zp_l[tid];
            #pragma unroll
            for (int w = 0; w < 8; ++w) s += red[(w * 4 + c) * 64 + b];
            hh_l[tid] = s;
        }
        __syncthreads();
        if (tid < 128) {
            int c = tid >> 5, pb = (tid & 31) << 1;
            coh_store2(&g_hhatT[(jb + c) * 64 + pb], hh_l[(c << 6) + pb], hh_l[(c << 6) + pb + 1]);
        }
        __syncthreads();   // vmcnt(0) drain: h_hat stores complete before arrive

        // ---- arrive A ----
        if (tid == 0)
            __hip_atomic_fetch_add(&g_bar[2 * t][barlane], 1u, __ATOMIC_RELAXED, __HIP_MEMORY_SCOPE_AGENT);

        // ---- gi(t+1), hidden under barrier A ----
        if (t + 1 < S_)
            gemm12n(g_xT + (size_t)(t + 1) * IN_ * B_, wX, bih_l, gi_nxt, red, tid);

        // ---- wait A ----
        if (tid == 0) {
            unsigned s;
            do {
                s = 0;
                #pragma unroll
                for (int i = 0; i < 8; ++i)
                    s += __hip_atomic_load(&g_bar[2 * t][i << 5], __ATOMIC_RELAXED, __HIP_MEMORY_SCOPE_AGENT);
                if (s < NBLK) __builtin_amdgcn_s_sleep(2);
            } while (s < NBLK);
        }
        __syncthreads();

        // ---- P2: gh, 12 cols over h_hat, K=1024, coherent pipelined ----
        gemm12c(g_hhatT, wB, bhh_l, gh_l, red, tid);
        __syncthreads();

        // ---- gates + writeback (threads 0..255) ----
        if (tid < 256) {
            int cc = tid >> 6, b = tid & 63;
            float hh = hh_l[tid];
            float hr = gh_l[cc * 64 + b];
            float hz = gh_l[(4 + cc) * 64 + b];
            float hn = gh_l[(8 + cc) * 64 + b];
            float ir = gi_cur[cc * 64 + b];
            float iz = gi_cur[(4 + cc) * 64 + b];
            float in_ = gi_cur[(8 + cc) * 64 + b];
            float r = 1.f / (1.f + expf(-(ir + hr)));
            float u = 1.f / (1.f + expf(-(iz + hz)));
            float n = tanhf(in_ + r * hn);
            float v = (1.f - u) * n + u * hh;
            hn_l[tid] = v;
            int j = jb + cc;
            out[((size_t)b * S_ + t) * H_ + j] = v;
            if (t == S_ - 1)
                out[(size_t)B_ * S_ * H_ + (size_t)b * H_ + j] = v;
        }
        __syncthreads();
        if (tid < 128) {
            int c = tid >> 5, pb = (tid & 31) << 1;
            coh_store2(&g_hT[(t + 1) & 1][(jb + c) * 64 + pb], hn_l[(c << 6) + pb], hn_l[(c << 6) + pb + 1]);
        }
        __syncthreads();   // vmcnt(0) drain: h stores complete before arrive

        // ---- arrive B + wait B ----
        if (tid == 0) {
            __hip_atomic_fetch_add(&g_bar[2 * t + 1][barlane], 1u, __ATOMIC_RELAXED, __HIP_MEMORY_SCOPE_AGENT);
            unsigned s;
            do {
                s = 0;
                #pragma unroll
                for (int i = 0; i < 8; ++i)
                    s += __hip_atomic_load(&g_bar[2 * t + 1][i << 5], __ATOMIC_RELAXED, __HIP_MEMORY_SCOPE_AGENT);
                if (s < NBLK) __builtin_amdgcn_s_sleep(2);
            } while (s < NBLK);
        }
        __syncthreads();
    }
}

extern "C" void kernel_launch(void* const* d_in, const int* in_sizes, int n_in,
                              void* d_out, int out_size, void* d_ws, size_t ws_size,
                              hipStream_t stream) {
    const float* inputs = (const float*)d_in[0];
    const float* h0     = (const float*)d_in[1];
    const float* z      = (const float*)d_in[2];
    const float* Wlin   = (const float*)d_in[3];
    const float* blin   = (const float*)d_in[4];
    const float* Wih    = (const float*)d_in[5];
    const float* bih    = (const float*)d_in[6];
    const float* Whh    = (const float*)d_in[7];
    const float* bhh    = (const float*)d_in[8];
    float* out = (float*)d_out;

    hipLaunchKernelGGL(pre_transpose_x, dim3(S_ * 8), dim3(256), 0, stream, inputs);
    hipLaunchKernelGGL(pre_misc, dim3(H_), dim3(64), 0, stream, z, Wlin, blin, h0);
    hipLaunchKernelGGL(skipgru_2ph, dim3(NBLK), dim3(NTHR), 0, stream,
                       Wlin, Wih, bih, Whh, bhh, out);
}

// Round 10
// 12569.213 us; speedup vs baseline: 6.4239x; 6.4239x over previous
//
#include <hip/hip_runtime.h>
#include <math.h>

#define B_   64
#define S_   512
#define IN_  512
#define H_   1024
#define WLK_ (H_ + 128)
#define NBLK 256
#define NTHR 512

typedef unsigned long long ull;

// ---- static device scratch ----
__device__ float g_xT[(size_t)S_ * IN_ * B_];   // [s][k][b]
__device__ float g_h0T[H_ * B_];                // [k][b]
__device__ float g_hT[2][H_ * B_];              // [k][b]
__device__ float g_hhatT[H_ * B_];              // [j][b]
__device__ float g_zprojT[H_ * B_];             // [j][b] includes b_lin
__device__ unsigned g_bar[2 * S_][256];         // 8 live counters/slot, 128B apart

// Device-coherent transport (R7-proven: L2-served, FETCH 1.3GB, correct).
// LESSON (R8/R9): do NOT hand-pipeline these with 16-32 named staging regs —
// both attempts spilled to scratch (WRITE_SIZE ~ FETCH_SIZE ~ 85GB, 4-7x slower).
// Keep pressure low; let the compiler schedule within moderate unroll.
__device__ __forceinline__ float4 coh_load4(const float* p) {
    const ull* q = (const ull*)p;
    ull u0 = __hip_atomic_load(q,     __ATOMIC_RELAXED, __HIP_MEMORY_SCOPE_AGENT);
    ull u1 = __hip_atomic_load(q + 1, __ATOMIC_RELAXED, __HIP_MEMORY_SCOPE_AGENT);
    union { ull u; float2 f; } a, b;
    a.u = u0; b.u = u1;
    return make_float4(a.f.x, a.f.y, b.f.x, b.f.y);
}
__device__ __forceinline__ void coh_store2(float* p, float x, float y) {
    union { float2 f; ull u; } v; v.f = make_float2(x, y);
    __hip_atomic_store((ull*)p, v.u, __ATOMIC_RELAXED, __HIP_MEMORY_SCOPE_AGENT);
}

// ---------------- prologue 1: transpose inputs [B][S][IN] -> xT [S][IN][B] ----
__global__ void pre_transpose_x(const float* __restrict__ in) {
    __shared__ float lds[64][65];
    int s  = blockIdx.x >> 3;
    int k0 = (blockIdx.x & 7) << 6;
    int tid = threadIdx.x;
    int kk = tid & 63, bq = tid >> 6;
    for (int b = bq; b < 64; b += 4)
        lds[kk][b] = in[((size_t)b * S_ + s) * IN_ + k0 + kk];
    __syncthreads();
    int bb = tid & 63, kq = tid >> 6;
    for (int k = kq; k < 64; k += 4)
        g_xT[((size_t)s * IN_ + k0 + k) * B_ + bb] = lds[k][bb];
}

// ---------------- prologue 2: z_projT (incl b_lin), h0T, zero barriers ------
__global__ void pre_misc(const float* __restrict__ z, const float* __restrict__ Wlin,
                         const float* __restrict__ blin, const float* __restrict__ h0) {
    __shared__ float zT[128][65];
    int j = blockIdx.x;      // 0..1023
    int b = threadIdx.x;     // 0..63
    for (int i = 0; i < 128; ++i) {
        int idx = b + (i << 6);
        zT[idx & 127][idx >> 7] = z[idx];
    }
    __syncthreads();
    float acc = blin[j];
    const float* w = Wlin + (size_t)j * WLK_ + H_;
    for (int k = 0; k < 128; ++k)
        acc = fmaf(zT[k][b], w[k], acc);
    g_zprojT[j * 64 + b] = acc;
    g_h0T[j * 64 + b]    = h0[(size_t)b * H_ + j];
    for (int i = b; i < 256; i += 64)
        g_bar[j][i] = 0;
}

#define F4(AC, WS) AC.x=fmaf(WS,a.x,AC.x); AC.y=fmaf(WS,a.y,AC.y); AC.z=fmaf(WS,a.z,AC.z); AC.w=fmaf(WS,a.w,AC.w);

// 12-col GEMM over K: dst[c*64+b] = bias_l[c] + sum_k wl[k][c]*src[k][b]
// COH: load src via agent-scope atomics (cross-block coherent data).
template<bool COH>
__device__ __forceinline__ void gemm12(const float* __restrict__ src,
                                       const float* wl, int K,
                                       const float* bias_l, float* dst,
                                       float* red, int tid) {
    const int bq = tid & 15, kq = tid >> 4;
    const int wv = tid >> 6, ln = tid & 63;
    const float* ap = src + (kq << 6) + (bq << 2);
    const float* wp = wl + kq * 12;
    float4 acc[12];
    #pragma unroll
    for (int c = 0; c < 12; ++c) acc[c] = make_float4(0.f, 0.f, 0.f, 0.f);
    const int iters = K >> 5;
    #pragma unroll 4
    for (int i = 0; i < iters; ++i) {
        float4 a = COH ? coh_load4(ap) : *(const float4*)ap;
        ap += 32 * 64;
        float4 w0 = *(const float4*)(wp + 0);
        float4 w1 = *(const float4*)(wp + 4);
        float4 w2 = *(const float4*)(wp + 8);  wp += 32 * 12;
        F4(acc[0],w0.x) F4(acc[1],w0.y) F4(acc[2],w0.z)  F4(acc[3],w0.w)
        F4(acc[4],w1.x) F4(acc[5],w1.y) F4(acc[6],w1.z)  F4(acc[7],w1.w)
        F4(acc[8],w2.x) F4(acc[9],w2.y) F4(acc[10],w2.z) F4(acc[11],w2.w)
    }
    #pragma unroll
    for (int c = 0; c < 12; ++c) {
        float4 v = acc[c];
        v.x += __shfl_xor(v.x,16); v.y += __shfl_xor(v.y,16);
        v.z += __shfl_xor(v.z,16); v.w += __shfl_xor(v.w,16);
        v.x += __shfl_xor(v.x,32); v.y += __shfl_xor(v.y,32);
        v.z += __shfl_xor(v.z,32); v.w += __shfl_xor(v.w,32);
        if (ln < 16) *(float4*)&red[(wv * 12 + c) * 64 + (ln << 2)] = v;
    }
    __syncthreads();
    for (int o = tid; o < 768; o += NTHR) {
        int c = o >> 6, b = o & 63;
        float s = bias_l[c];
        #pragma unroll
        for (int w = 0; w < 8; ++w) s += red[(w * 12 + c) * 64 + b];
        dst[o] = s;
    }
}

// ---------------- persistent recurrence kernel ------------------------------
// 256 blocks x 512 threads; block owns hidden cols j = 4*blk..+3.
// 2-phase step: P1 h_hat | barrier A (gi hidden) | P2 gh + gates |
// barrier B (out-write hidden). No agent fences: cross-block data moves via
// relaxed agent-scope atomics; __syncthreads' vmcnt(0) drain orders stores
// before the arrive-add.
__launch_bounds__(NTHR, 1)
__global__ void skipgru_2ph(const float* __restrict__ Wlin, const float* __restrict__ Wih,
                            const float* __restrict__ bih,  const float* __restrict__ Whh,
                            const float* __restrict__ bhh,  float* __restrict__ out) {
    __shared__ float wA[H_ * 4];        // 16 KB [k][c<4]
    __shared__ float wB[H_ * 12];       // 48 KB [k][c<12]
    __shared__ float wX[IN_ * 12];      // 24 KB [k][c<12]
    __shared__ float red[8 * 12 * 64];  // 24 KB
    __shared__ float gh_l[12 * 64];
    __shared__ float gi_a[12 * 64];
    __shared__ float gi_b[12 * 64];
    __shared__ float hh_l[4 * 64];
    __shared__ float hn_l[4 * 64];
    __shared__ float zp_l[4 * 64];
    __shared__ float bhh_l[12];
    __shared__ float bih_l[12];

    const int tid = threadIdx.x;
    const int jb  = blockIdx.x << 2;
    const int bq  = tid & 15;
    const int kq  = tid >> 4;
    const int wv  = tid >> 6, ln = tid & 63;
    const int barlane = (blockIdx.x & 7) << 5;

    for (int c = 0; c < 4; ++c) {
        const float* src = Wlin + (size_t)(jb + c) * WLK_;
        for (int k = tid; k < H_; k += NTHR) wA[k * 4 + c] = src[k];
    }
    for (int c = 0; c < 12; ++c) {
        const float* src = Whh + (size_t)((c >> 2) * H_ + jb + (c & 3)) * H_;
        for (int k = tid; k < H_; k += NTHR) wB[k * 12 + c] = src[k];
    }
    for (int c = 0; c < 12; ++c) {
        const float* src = Wih + (size_t)((c >> 2) * H_ + jb + (c & 3)) * IN_;
        for (int k = tid; k < IN_; k += NTHR) wX[k * 12 + c] = src[k];
    }
    if (tid < 256) zp_l[tid] = g_zprojT[(jb + (tid >> 6)) * 64 + (tid & 63)];
    if (tid < 12) {
        bhh_l[tid] = bhh[(tid >> 2) * H_ + jb + (tid & 3)];
        bih_l[tid] = bih[(tid >> 2) * H_ + jb + (tid & 3)];
    }
    __syncthreads();

    gemm12<false>(g_xT, wX, IN_, bih_l, gi_a, red, tid);
    __syncthreads();

    for (int t = 0; t < S_; ++t) {
        const float* hs = (t == 0) ? g_h0T : g_hT[t & 1];
        const float* gi_cur = (t & 1) ? gi_b : gi_a;
        float*       gi_nxt = (t & 1) ? gi_a : gi_b;

        // ---- P1: h_hat, 4 cols, K=1024 (coherent h loads, unroll 8) ----
        {
            const float* ap = hs + (kq << 6) + (bq << 2);
            const float* wp = wA + kq * 4;
            float4 acc[4];
            #pragma unroll
            for (int c = 0; c < 4; ++c) acc[c] = make_float4(0.f, 0.f, 0.f, 0.f);
            #pragma unroll 8
            for (int i = 0; i < 32; ++i) {
                float4 a = coh_load4(ap);  ap += 32 * 64;
                float4 w = *(const float4*)wp;  wp += 32 * 4;
                F4(acc[0],w.x) F4(acc[1],w.y) F4(acc[2],w.z) F4(acc[3],w.w)
            }
            #pragma unroll
            for (int c = 0; c < 4; ++c) {
                float4 v = acc[c];
                v.x += __shfl_xor(v.x,16); v.y += __shfl_xor(v.y,16);
                v.z += __shfl_xor(v.z,16); v.w += __shfl_xor(v.w,16);
                v.x += __shfl_xor(v.x,32); v.y += __shfl_xor(v.y,32);
                v.z += __shfl_xor(v.z,32); v.w += __shfl_xor(v.w,32);
                if (ln < 16) *(float4*)&red[(wv * 4 + c) * 64 + (ln << 2)] = v;
            }
        }
        __syncthreads();
        if (tid < 256) {
            int c = tid >> 6, b = tid & 63;
            float s = zp_l[tid];
            #pragma unroll
            for (int w = 0; w < 8; ++w) s += red[(w * 4 + c) * 64 + b];
            hh_l[tid] = s;
        }
        __syncthreads();
        if (tid < 128) {
            int c = tid >> 5, pb = (tid & 31) << 1;
            coh_store2(&g_hhatT[(jb + c) * 64 + pb], hh_l[(c << 6) + pb], hh_l[(c << 6) + pb + 1]);
        }
        __syncthreads();   // vmcnt(0) drain: h_hat stores complete before arrive

        // ---- arrive A ----
        if (tid == 0)
            __hip_atomic_fetch_add(&g_bar[2 * t][barlane], 1u, __ATOMIC_RELAXED, __HIP_MEMORY_SCOPE_AGENT);

        // ---- gi(t+1), hidden under barrier A ----
        if (t + 1 < S_)
            gemm12<false>(g_xT + (size_t)(t + 1) * IN_ * B_, wX, IN_, bih_l, gi_nxt, red, tid);

        // ---- wait A ----
        if (tid == 0) {
            unsigned s;
            do {
                s = 0;
                #pragma unroll
                for (int i = 0; i < 8; ++i)
                    s += __hip_atomic_load(&g_bar[2 * t][i << 5], __ATOMIC_RELAXED, __HIP_MEMORY_SCOPE_AGENT);
                if (s < NBLK) __builtin_amdgcn_s_sleep(2);
            } while (s < NBLK);
        }
        __syncthreads();

        // ---- P2: gh, 12 cols over h_hat, K=1024 (coherent) ----
        gemm12<true>(g_hhatT, wB, H_, bhh_l, gh_l, red, tid);
        __syncthreads();

        // ---- gates (threads 0..255) ----
        if (tid < 256) {
            int cc = tid >> 6, b = tid & 63;
            float hh = hh_l[tid];
            float hr = gh_l[cc * 64 + b];
            float hz = gh_l[(4 + cc) * 64 + b];
            float hn = gh_l[(8 + cc) * 64 + b];
            float ir = gi_cur[cc * 64 + b];
            float iz = gi_cur[(4 + cc) * 64 + b];
            float in_ = gi_cur[(8 + cc) * 64 + b];
            float r = 1.f / (1.f + expf(-(ir + hr)));
            float u = 1.f / (1.f + expf(-(iz + hz)));
            float n = tanhf(in_ + r * hn);
            float v = (1.f - u) * n + u * hh;
            hn_l[tid] = v;
        }
        __syncthreads();
        if (tid < 128) {
            int c = tid >> 5, pb = (tid & 31) << 1;
            coh_store2(&g_hT[(t + 1) & 1][(jb + c) * 64 + pb], hn_l[(c << 6) + pb], hn_l[(c << 6) + pb + 1]);
        }
        __syncthreads();   // vmcnt(0) drain: h stores complete before arrive

        // ---- arrive B ----
        if (tid == 0)
            __hip_atomic_fetch_add(&g_bar[2 * t + 1][barlane], 1u, __ATOMIC_RELAXED, __HIP_MEMORY_SCOPE_AGENT);

        // ---- out write, hidden under barrier B (reads only hn_l) ----
        if (tid < 256) {
            int cc = tid >> 6, b = tid & 63;
            int j = jb + cc;
            float v = hn_l[tid];
            out[((size_t)b * S_ + t) * H_ + j] = v;
            if (t == S_ - 1)
                out[(size_t)B_ * S_ * H_ + (size_t)b * H_ + j] = v;
        }

        // ---- wait B ----
        if (tid == 0) {
            unsigned s;
            do {
                s = 0;
                #pragma unroll
                for (int i = 0; i < 8; ++i)
                    s += __hip_atomic_load(&g_bar[2 * t + 1][i << 5], __ATOMIC_RELAXED, __HIP_MEMORY_SCOPE_AGENT);
                if (s < NBLK) __builtin_amdgcn_s_sleep(2);
            } while (s < NBLK);
        }
        __syncthreads();
    }
}

extern "C" void kernel_launch(void* const* d_in, const int* in_sizes, int n_in,
                              void* d_out, int out_size, void* d_ws, size_t ws_size,
                              hipStream_t stream) {
    const float* inputs = (const float*)d_in[0];
    const float* h0     = (const float*)d_in[1];
    const float* z      = (const float*)d_in[2];
    const float* Wlin   = (const float*)d_in[3];
    const float* blin   = (const float*)d_in[4];
    const float* Wih    = (const float*)d_in[5];
    const float* bih    = (const float*)d_in[6];
    const float* Whh    = (const float*)d_in[7];
    const float* bhh    = (const float*)d_in[8];
    float* out = (float*)d_out;

    hipLaunchKernelGGL(pre_transpose_x, dim3(S_ * 8), dim3(256), 0, stream, inputs);
    hipLaunchKernelGGL(pre_misc, dim3(H_), dim3(64), 0, stream, z, Wlin, blin, h0);
    hipLaunchKernelGGL(skipgru_2ph, dim3(NBLK), dim3(NTHR), 0, stream,
                       Wlin, Wih, bih, Whh, bhh, out);
}

// Round 11
// 12388.136 us; speedup vs baseline: 6.5178x; 1.0146x over previous
//
#include <hip/hip_runtime.h>
#include <math.h>

#define B_   64
#define S_   512
#define IN_  512
#define H_   1024
#define WLK_ (H_ + 128)
#define NBLK 256
#define NTHR 512
#define NSLOT 16
#define SLOTF (H_ * B_)

typedef unsigned long long ull;

// ---- static device scratch ----
__device__ float g_xT[(size_t)S_ * IN_ * B_];   // [s][k][b]
__device__ float g_h0T[H_ * B_];                // [k][b]
__device__ float g_hT[2][H_ * B_];              // [k][b]  (coherent, L3)
__device__ float g_hhatT[H_ * B_];              // [j][b]  (coherent, L3)
__device__ float g_zprojT[H_ * B_];             // [j][b] includes b_lin
__device__ float g_stage[8][NSLOT][SLOTF];      // per-XCD L2 staging ring (32MB)
__device__ unsigned g_bar[2 * S_ + 1][256];     // global barrier, 8 live ctrs/slot
__device__ unsigned g_xbar[8][2 * S_ + 2];      // per-XCD barrier slots
__device__ unsigned g_xcdrank[8];

// Coherent 8B ops (R7-proven: MALL-served, correct). Used ONLY for the tiny
// publish/copy traffic now — bulk GEMM reads go through per-XCD L2 staging.
__device__ __forceinline__ ull coh_ld(const ull* p) {
    return __hip_atomic_load(p, __ATOMIC_RELAXED, __HIP_MEMORY_SCOPE_AGENT);
}
__device__ __forceinline__ void coh_store2(float* p, float x, float y) {
    union { float2 f; ull u; } v; v.f = make_float2(x, y);
    __hip_atomic_store((ull*)p, v.u, __ATOMIC_RELAXED, __HIP_MEMORY_SCOPE_AGENT);
}

// ---------------- prologue 1: transpose inputs [B][S][IN] -> xT [S][IN][B] ----
__global__ void pre_transpose_x(const float* __restrict__ in) {
    __shared__ float lds[64][65];
    int s  = blockIdx.x >> 3;
    int k0 = (blockIdx.x & 7) << 6;
    int tid = threadIdx.x;
    int kk = tid & 63, bq = tid >> 6;
    for (int b = bq; b < 64; b += 4)
        lds[kk][b] = in[((size_t)b * S_ + s) * IN_ + k0 + kk];
    __syncthreads();
    int bb = tid & 63, kq = tid >> 6;
    for (int k = kq; k < 64; k += 4)
        g_xT[((size_t)s * IN_ + k0 + k) * B_ + bb] = lds[k][bb];
}

// ---------------- prologue 2: z_projT (incl b_lin), h0T, zero sync state ----
__global__ void pre_misc(const float* __restrict__ z, const float* __restrict__ Wlin,
                         const float* __restrict__ blin, const float* __restrict__ h0) {
    __shared__ float zT[128][65];
    int j = blockIdx.x;      // 0..1023
    int b = threadIdx.x;     // 0..63
    for (int i = 0; i < 128; ++i) {
        int idx = b + (i << 6);
        zT[idx & 127][idx >> 7] = z[idx];
    }
    __syncthreads();
    float acc = blin[j];
    const float* w = Wlin + (size_t)j * WLK_ + H_;
    for (int k = 0; k < 128; ++k)
        acc = fmaf(zT[k][b], w[k], acc);
    g_zprojT[j * 64 + b] = acc;
    g_h0T[j * 64 + b]    = h0[(size_t)b * H_ + j];
    for (int r = j; r < 2 * S_ + 1; r += H_)
        for (int i = b; i < 256; i += 64) g_bar[r][i] = 0;
    if (j < 8) {
        for (int i = b; i < 2 * S_ + 2; i += 64) g_xbar[j][i] = 0;
        if (b == 0) g_xcdrank[j] = 0;
    }
}

#define F4(AC, WS) AC.x=fmaf(WS,a.x,AC.x); AC.y=fmaf(WS,a.y,AC.y); AC.z=fmaf(WS,a.z,AC.z); AC.w=fmaf(WS,a.w,AC.w);

// 12-col GEMM over K, plain cached loads: dst[c*64+b] = bias[c] + sum_k wl[k][c]*src[k][b]
__device__ __forceinline__ void gemm12(const float* __restrict__ src,
                                       const float* wl, int K,
                                       const float* bias_l, float* dst,
                                       float* red, int tid) {
    const int bq = tid & 15, kq = tid >> 4;
    const int wv = tid >> 6, ln = tid & 63;
    const float* ap = src + (kq << 6) + (bq << 2);
    const float* wp = wl + kq * 12;
    float4 acc[12];
    #pragma unroll
    for (int c = 0; c < 12; ++c) acc[c] = make_float4(0.f, 0.f, 0.f, 0.f);
    const int iters = K >> 5;
    #pragma unroll 4
    for (int i = 0; i < iters; ++i) {
        float4 a = *(const float4*)ap;  ap += 32 * 64;
        float4 w0 = *(const float4*)(wp + 0);
        float4 w1 = *(const float4*)(wp + 4);
        float4 w2 = *(const float4*)(wp + 8);  wp += 32 * 12;
        F4(acc[0],w0.x) F4(acc[1],w0.y) F4(acc[2],w0.z)  F4(acc[3],w0.w)
        F4(acc[4],w1.x) F4(acc[5],w1.y) F4(acc[6],w1.z)  F4(acc[7],w1.w)
        F4(acc[8],w2.x) F4(acc[9],w2.y) F4(acc[10],w2.z) F4(acc[11],w2.w)
    }
    #pragma unroll
    for (int c = 0; c < 12; ++c) {
        float4 v = acc[c];
        v.x += __shfl_xor(v.x,16); v.y += __shfl_xor(v.y,16);
        v.z += __shfl_xor(v.z,16); v.w += __shfl_xor(v.w,16);
        v.x += __shfl_xor(v.x,32); v.y += __shfl_xor(v.y,32);
        v.z += __shfl_xor(v.z,32); v.w += __shfl_xor(v.w,32);
        if (ln < 16) *(float4*)&red[(wv * 12 + c) * 64 + (ln << 2)] = v;
    }
    __syncthreads();
    for (int o = tid; o < 768; o += NTHR) {
        int c = o >> 6, b = o & 63;
        float s = bias_l[c];
        #pragma unroll
        for (int w = 0; w < 8; ++w) s += red[(w * 12 + c) * 64 + b];
        dst[o] = s;
    }
}

// copy one 256KB vector from coherent global -> this XCD's stage slot.
// 32 chunks of 2048 floats; rank r takes chunks r, r+nx, ... (robust to nx!=32)
__device__ __forceinline__ void xcopy(const float* __restrict__ gsrc,
                                      float* __restrict__ ldst,
                                      int rank, int nx, int tid) {
    for (int c = rank; c < 32; c += nx) {
        const ull* s = (const ull*)gsrc + (c << 10) + (tid << 1);
        ull a = coh_ld(s);
        ull b = coh_ld(s + 1);
        ull* d = (ull*)ldst + (c << 10) + (tid << 1);
        d[0] = a; d[1] = b;
    }
}

// global barrier: arrive (tid0) ... hidden work ... wait (8 lanes poll the 8
// split counters in PARALLEL — one vector atomic load per poll round)
__device__ __forceinline__ void gbar_wait(int slot, int tid) {
    if (tid < 8) {
        while ((int)__hip_atomic_load(&g_bar[slot][tid << 5], __ATOMIC_RELAXED, __HIP_MEMORY_SCOPE_AGENT) < 32)
            __builtin_amdgcn_s_sleep(1);
    }
    __syncthreads();
    asm volatile("" ::: "memory");
}

// per-XCD barrier: drain stage stores (syncthreads -> vmcnt(0)), then flag.
// Same-L2 visibility: stores landed in this XCD's L2 before the (farther) L3
// flag became visible — R7-proven ordering pattern.
__device__ __forceinline__ void xbar_sync(int xcd, int slot, int nx, int tid) {
    asm volatile("" ::: "memory");
    __syncthreads();
    if (tid == 0) {
        __hip_atomic_fetch_add(&g_xbar[xcd][slot], 1u, __ATOMIC_RELAXED, __HIP_MEMORY_SCOPE_AGENT);
        while ((int)__hip_atomic_load(&g_xbar[xcd][slot], __ATOMIC_RELAXED, __HIP_MEMORY_SCOPE_AGENT) < nx)
            __builtin_amdgcn_s_sleep(1);
    }
    __syncthreads();
    asm volatile("" ::: "memory");
}

// ---------------- persistent recurrence kernel ------------------------------
// 256 blocks x 512 threads, 1 block/CU (LDS-forced) => exactly 32 blocks/XCD.
// Cross-XCD state moves via coherent L3 publish (1KB/block) + per-XCD L2
// staging copies (8KB/block); bulk GEMM reads are plain L2 hits.
__launch_bounds__(NTHR, 1)
__global__ void skipgru_2ph(const float* __restrict__ Wlin, const float* __restrict__ Wih,
                            const float* __restrict__ bih,  const float* __restrict__ Whh,
                            const float* __restrict__ bhh,  float* __restrict__ out) {
    __shared__ float wA[H_ * 4];        // 16 KB [k][c<4]
    __shared__ float wB[H_ * 12];       // 48 KB [k][c<12]
    __shared__ float wX[IN_ * 12];      // 24 KB [k][c<12]
    __shared__ float red[8 * 12 * 64];  // 24 KB
    __shared__ float gh_l[12 * 64];
    __shared__ float gi_a[12 * 64];
    __shared__ float gi_b[12 * 64];
    __shared__ float hh_l[4 * 64];
    __shared__ float hn_l[4 * 64];
    __shared__ float zp_l[4 * 64];
    __shared__ float bhh_l[12];
    __shared__ float bih_l[12];
    __shared__ int s_info[3];           // xcd, rank, nx

    const int tid = threadIdx.x;
    const int jb  = blockIdx.x << 2;
    const int bq  = tid & 15;
    const int kq  = tid >> 4;
    const int wv  = tid >> 6, ln = tid & 63;
    const int barlane = (blockIdx.x & 7) << 5;

    // ---- XCD identity + rank (runtime, no dispatch assumptions) ----
    if (tid == 0) {
        unsigned xcd;
        asm volatile("s_getreg_b32 %0, hwreg(HW_REG_XCC_ID)" : "=s"(xcd));
        xcd &= 7;
        s_info[0] = (int)xcd;
        s_info[1] = (int)__hip_atomic_fetch_add(&g_xcdrank[xcd], 1u,
                        __ATOMIC_RELAXED, __HIP_MEMORY_SCOPE_AGENT);
    }

    // ---- stage weights ----
    for (int c = 0; c < 4; ++c) {
        const float* src = Wlin + (size_t)(jb + c) * WLK_;
        for (int k = tid; k < H_; k += NTHR) wA[k * 4 + c] = src[k];
    }
    for (int c = 0; c < 12; ++c) {
        const float* src = Whh + (size_t)((c >> 2) * H_ + jb + (c & 3)) * H_;
        for (int k = tid; k < H_; k += NTHR) wB[k * 12 + c] = src[k];
    }
    for (int c = 0; c < 12; ++c) {
        const float* src = Wih + (size_t)((c >> 2) * H_ + jb + (c & 3)) * IN_;
        for (int k = tid; k < IN_; k += NTHR) wX[k * 12 + c] = src[k];
    }
    if (tid < 256) zp_l[tid] = g_zprojT[(jb + (tid >> 6)) * 64 + (tid & 63)];
    if (tid < 12) {
        bhh_l[tid] = bhh[(tid >> 2) * H_ + jb + (tid & 3)];
        bih_l[tid] = bih[(tid >> 2) * H_ + jb + (tid & 3)];
    }
    __syncthreads();
    const int xcd = s_info[0], rank = s_info[1];

    // ---- prologue global barrier: all ranks assigned ----
    if (tid == 0)
        __hip_atomic_fetch_add(&g_bar[2 * S_][barlane], 1u, __ATOMIC_RELAXED, __HIP_MEMORY_SCOPE_AGENT);
    gbar_wait(2 * S_, tid);
    if (tid == 0)
        s_info[2] = (int)__hip_atomic_load(&g_xcdrank[xcd], __ATOMIC_RELAXED, __HIP_MEMORY_SCOPE_AGENT);
    __syncthreads();
    const int nx = s_info[2];
    float* const stg = &g_stage[xcd][0][0];

    // ---- h0 -> stage slot 0 ----
    xcopy(g_h0T, stg, rank, nx, tid);
    xbar_sync(xcd, 2 * S_, nx, tid);

    // ---- gi(0) -> gi_a ----
    gemm12(g_xT, wX, IN_, bih_l, gi_a, red, tid);
    __syncthreads();

    for (int t = 0; t < S_; ++t) {
        const float* gi_cur = (t & 1) ? gi_b : gi_a;
        float*       gi_nxt = (t & 1) ? gi_a : gi_b;
        const float* stgA = stg + ((2 * t)     & (NSLOT - 1)) * SLOTF;
        float*       stgB = stg + ((2 * t + 1) & (NSLOT - 1)) * SLOTF;
        float*       stgN = stg + ((2 * t + 2) & (NSLOT - 1)) * SLOTF;

        // ---- P1: h_hat, 4 cols, K=1024 (plain L2-hit loads from stage) ----
        {
            const float* ap = stgA + (kq << 6) + (bq << 2);
            const float* wp = wA + kq * 4;
            float4 acc[4];
            #pragma unroll
            for (int c = 0; c < 4; ++c) acc[c] = make_float4(0.f, 0.f, 0.f, 0.f);
            #pragma unroll 8
            for (int i = 0; i < 32; ++i) {
                float4 a = *(const float4*)ap;  ap += 32 * 64;
                float4 w = *(const float4*)wp;  wp += 32 * 4;
                F4(acc[0],w.x) F4(acc[1],w.y) F4(acc[2],w.z) F4(acc[3],w.w)
            }
            #pragma unroll
            for (int c = 0; c < 4; ++c) {
                float4 v = acc[c];
                v.x += __shfl_xor(v.x,16); v.y += __shfl_xor(v.y,16);
                v.z += __shfl_xor(v.z,16); v.w += __shfl_xor(v.w,16);
                v.x += __shfl_xor(v.x,32); v.y += __shfl_xor(v.y,32);
                v.z += __shfl_xor(v.z,32); v.w += __shfl_xor(v.w,32);
                if (ln < 16) *(float4*)&red[(wv * 4 + c) * 64 + (ln << 2)] = v;
            }
        }
        __syncthreads();
        if (tid < 256) {
            int c = tid >> 6, b = tid & 63;
            float s = zp_l[tid];
            #pragma unroll
            for (int w = 0; w < 8; ++w) s += red[(w * 4 + c) * 64 + b];
            hh_l[tid] = s;
        }
        __syncthreads();
        if (tid < 128) {
            int c = tid >> 5, pb = (tid & 31) << 1;
            coh_store2(&g_hhatT[(jb + c) * 64 + pb], hh_l[(c << 6) + pb], hh_l[(c << 6) + pb + 1]);
        }
        __syncthreads();   // vmcnt(0) drain: h_hat publish complete before arrive

        // ---- arrive A ----
        if (tid == 0)
            __hip_atomic_fetch_add(&g_bar[2 * t][barlane], 1u, __ATOMIC_RELAXED, __HIP_MEMORY_SCOPE_AGENT);

        // ---- gi(t+1), hidden under barrier A ----
        if (t + 1 < S_)
            gemm12(g_xT + (size_t)(t + 1) * IN_ * B_, wX, IN_, bih_l, gi_nxt, red, tid);

        // ---- wait A, then stage h_hat into this XCD's L2 ----
        gbar_wait(2 * t, tid);
        xcopy(g_hhatT, stgB, rank, nx, tid);
        xbar_sync(xcd, 2 * t, nx, tid);

        // ---- P2: gh, 12 cols over staged h_hat, K=1024 ----
        gemm12(stgB, wB, H_, bhh_l, gh_l, red, tid);
        __syncthreads();

        // ---- gates (threads 0..255) ----
        if (tid < 256) {
            int cc = tid >> 6, b = tid & 63;
            float hh = hh_l[tid];
            float hr = gh_l[cc * 64 + b];
            float hz = gh_l[(4 + cc) * 64 + b];
            float hn = gh_l[(8 + cc) * 64 + b];
            float ir = gi_cur[cc * 64 + b];
            float iz = gi_cur[(4 + cc) * 64 + b];
            float in_ = gi_cur[(8 + cc) * 64 + b];
            float r = 1.f / (1.f + expf(-(ir + hr)));
            float u = 1.f / (1.f + expf(-(iz + hz)));
            float n = tanhf(in_ + r * hn);
            float v = (1.f - u) * n + u * hh;
            hn_l[tid] = v;
        }
        __syncthreads();
        if (tid < 128) {
            int c = tid >> 5, pb = (tid & 31) << 1;
            coh_store2(&g_hT[(t + 1) & 1][(jb + c) * 64 + pb], hn_l[(c << 6) + pb], hn_l[(c << 6) + pb + 1]);
        }
        __syncthreads();   // vmcnt(0) drain: h publish complete before arrive

        // ---- arrive B ----
        if (tid == 0)
            __hip_atomic_fetch_add(&g_bar[2 * t + 1][barlane], 1u, __ATOMIC_RELAXED, __HIP_MEMORY_SCOPE_AGENT);

        // ---- out write, hidden under barrier B ----
        if (tid < 256) {
            int cc = tid >> 6, b = tid & 63;
            int j = jb + cc;
            float v = hn_l[tid];
            out[((size_t)b * S_ + t) * H_ + j] = v;
            if (t == S_ - 1)
                out[(size_t)B_ * S_ * H_ + (size_t)b * H_ + j] = v;
        }

        // ---- wait B, then stage h_new for next step's P1 ----
        gbar_wait(2 * t + 1, tid);
        if (t + 1 < S_) {
            xcopy(g_hT[(t + 1) & 1], stgN, rank, nx, tid);
            xbar_sync(xcd, 2 * t + 1, nx, tid);
        }
    }
}

extern "C" void kernel_launch(void* const* d_in, const int* in_sizes, int n_in,
                              void* d_out, int out_size, void* d_ws, size_t ws_size,
                              hipStream_t stream) {
    const float* inputs = (const float*)d_in[0];
    const float* h0     = (const float*)d_in[1];
    const float* z      = (const float*)d_in[2];
    const float* Wlin   = (const float*)d_in[3];
    const float* blin   = (const float*)d_in[4];
    const float* Wih    = (const float*)d_in[5];
    const float* bih    = (const float*)d_in[6];
    const float* Whh    = (const float*)d_in[7];
    const float* bhh    = (const float*)d_in[8];
    float* out = (float*)d_out;

    hipLaunchKernelGGL(pre_transpose_x, dim3(S_ * 8), dim3(256), 0, stream, inputs);
    hipLaunchKernelGGL(pre_misc, dim3(H_), dim3(64), 0, stream, z, Wlin, blin, h0);
    hipLaunchKernelGGL(skipgru_2ph, dim3(NBLK), dim3(NTHR), 0, stream,
                       Wlin, Wih, bih, Whh, bhh, out);
}